// Round 1
// baseline (1752.529 us; speedup 1.0000x reference)
//
#include <hip/hip_runtime.h>

#define THREADS 512
#define LVLS 16
#define TSZ 524288u
#define TMASK 524287u
#define PRIME1 2654435761u
#define DIN 204
#define HID 64

constexpr float resf(int l) { double r = 16.0; for (int i = 0; i < l; ++i) r *= 1.3819; return (float)r; }

__device__ __constant__ float c_RES[LVLS] = {
    resf(0),  resf(1),  resf(2),  resf(3),
    resf(4),  resf(5),  resf(6),  resf(7),
    resf(8),  resf(9),  resf(10), resf(11),
    resf(12), resf(13), resf(14), resf(15)
};

__global__ __launch_bounds__(THREADS, 4) void fused_hashmlp(
    const float* __restrict__ pxy, const float* __restrict__ pxz,
    const float* __restrict__ pyz, const float* __restrict__ pxt,
    const float* __restrict__ pyt, const float* __restrict__ pzt,
    const float* __restrict__ tables, const float* __restrict__ W1,
    const float* __restrict__ W2, const float* __restrict__ W3,
    float* __restrict__ out, int npts)
{
    __shared__ float sW1[DIN * HID];      // [204][64] row-major, 52224 B
    __shared__ float sW2T[HID * HID];     // transposed: [m][k], 16384 B
    __shared__ float sW3[HID * 3];        // 768 B

    const int tid = threadIdx.x;
    // Cooperative weight staging (once per block).
    for (int i = tid; i < DIN * HID / 4; i += THREADS)
        ((float4*)sW1)[i] = ((const float4*)W1)[i];
    for (int i = tid; i < HID * HID; i += THREADS)
        sW2T[(i & 63) * HID + (i >> 6)] = W2[i];   // sW2T[m][k] = W2[k][m]
    for (int i = tid; i < HID * 3; i += THREADS)
        sW3[i] = W3[i];
    __syncthreads();

    const int gid = blockIdx.x * THREADS + tid;

    float h1[HID];
    #pragma unroll
    for (int k = 0; k < HID; ++k) h1[k] = 0.f;

    const float* ptsArr[6] = { pxy, pxz, pyz, pxt, pyt, pzt };

    #pragma unroll
    for (int s = 0; s < 6; ++s) {
        const float px = ptsArr[s][2 * gid];
        const float py = ptsArr[s][2 * gid + 1];
        const float2* tbase = ((const float2*)tables) + (size_t)s * LVLS * TSZ;

        #pragma unroll 1
        for (int l = 0; l < LVLS; ++l) {
            const float r = c_RES[l];
            const float fx = px * r, fy = py * r;
            const float flx = floorf(fx), fly = floorf(fy);
            const float wx = fx - flx, wy = fy - fly;
            const unsigned x0 = (unsigned)(int)flx;
            const unsigned y0 = (unsigned)(int)fly;
            const unsigned hy0 = y0 * PRIME1;
            const unsigned hy1 = (y0 + 1u) * PRIME1;
            const float2* tab = tbase + (size_t)l * TSZ;

            const float2 f00 = tab[(x0 ^ hy0) & TMASK];
            const float2 f10 = tab[((x0 + 1u) ^ hy0) & TMASK];
            const float2 f01 = tab[(x0 ^ hy1) & TMASK];
            const float2 f11 = tab[((x0 + 1u) ^ hy1) & TMASK];

            const float w00 = (1.f - wx) * (1.f - wy);
            const float w10 = wx * (1.f - wy);
            const float w01 = (1.f - wx) * wy;
            const float w11 = wx * wy;
            const float e0 = f00.x * w00 + f10.x * w10 + f01.x * w01 + f11.x * w11;
            const float e1 = f00.y * w00 + f10.y * w10 + f01.y * w01 + f11.y * w11;

            // enc columns j = s*34 + 2l (+1); rank-1 update into h1.
            const float4* wr = (const float4*)&sW1[(s * 34 + 2 * l) * HID];
            #pragma unroll
            for (int q = 0; q < 16; ++q) {
                const float4 a = wr[q];       // row j,   cols 4q..4q+3
                const float4 b = wr[16 + q];  // row j+1, cols 4q..4q+3
                h1[4 * q + 0] += e0 * a.x + e1 * b.x;
                h1[4 * q + 1] += e0 * a.y + e1 * b.y;
                h1[4 * q + 2] += e0 * a.z + e1 * b.z;
                h1[4 * q + 3] += e0 * a.w + e1 * b.w;
            }
        }
        // raw coords: columns s*34+32, s*34+33
        const float4* wc = (const float4*)&sW1[(s * 34 + 32) * HID];
        #pragma unroll
        for (int q = 0; q < 16; ++q) {
            const float4 a = wc[q];
            const float4 b = wc[16 + q];
            h1[4 * q + 0] += px * a.x + py * b.x;
            h1[4 * q + 1] += px * a.y + py * b.y;
            h1[4 * q + 2] += px * a.z + py * b.z;
            h1[4 * q + 3] += px * a.w + py * b.w;
        }
    }

    #pragma unroll
    for (int k = 0; k < HID; ++k) h1[k] = fmaxf(h1[k], 0.f);

    float o0 = 0.f, o1 = 0.f, o2 = 0.f;
    #pragma unroll 1
    for (int m = 0; m < HID; ++m) {
        const float4* wrow = (const float4*)&sW2T[m * HID];
        float t = 0.f;
        #pragma unroll
        for (int q = 0; q < 16; ++q) {
            const float4 a = wrow[q];
            t += h1[4 * q + 0] * a.x + h1[4 * q + 1] * a.y
               + h1[4 * q + 2] * a.z + h1[4 * q + 3] * a.w;
        }
        t = fmaxf(t, 0.f);
        o0 += t * sW3[3 * m + 0];
        o1 += t * sW3[3 * m + 1];
        o2 += t * sW3[3 * m + 2];
    }

    if (gid < npts) {
        out[3 * gid + 0] = o0;
        out[3 * gid + 1] = o1;
        out[3 * gid + 2] = o2;
    }
}

extern "C" void kernel_launch(void* const* d_in, const int* in_sizes, int n_in,
                              void* d_out, int out_size, void* d_ws, size_t ws_size,
                              hipStream_t stream)
{
    const float* pxy = (const float*)d_in[0];
    const float* pxz = (const float*)d_in[1];
    const float* pyz = (const float*)d_in[2];
    const float* pxt = (const float*)d_in[3];
    const float* pyt = (const float*)d_in[4];
    const float* pzt = (const float*)d_in[5];
    const float* tables = (const float*)d_in[6];
    const float* W1 = (const float*)d_in[7];
    const float* W2 = (const float*)d_in[8];
    const float* W3 = (const float*)d_in[9];
    float* out = (float*)d_out;

    const int npts = in_sizes[0] / 2;
    const int grid = (npts + THREADS - 1) / THREADS;

    hipLaunchKernelGGL(fused_hashmlp, dim3(grid), dim3(THREADS), 0, stream,
                       pxy, pxz, pyz, pxt, pyt, pzt, tables, W1, W2, W3, out, npts);
}